// Round 4
// baseline (77907.861 us; speedup 1.0000x reference)
//
#include <hip/hip_runtime.h>
#include <math.h>

#define NN 2048   // 2L
#define LL 1024   // L
#define NSWB 10   // blocked Jacobi sweeps (skip logic makes converged sweeps cheap)
#define PITER 10  // power iterations for spectral radius
#define JTAU 1e-10f  // relative off^2 threshold: |apq|_rel < 1e-5 -> identity.
                     // fp32 Gram noise floor is ~2.7e-6 rel, so converged blocks
                     // genuinely skip (R3's 1e-11 sat AT the noise floor; never fired)

// ---------------------------------------------------------------------------
// Build W = (H0 + H0^T)/2  (eigh symmetrizes input; phonon part asymmetric).
// Column p contiguous at W + p*NN (symmetric).
// ---------------------------------------------------------------------------
__global__ void build_H(const float* __restrict__ hop,  const float* __restrict__ swm,
                        const float* __restrict__ dwm,  const float* __restrict__ hv,
                        const float* __restrict__ sv,   const float* __restrict__ dv,
                        const float* __restrict__ X,    const float* __restrict__ Y,
                        const int*   __restrict__ ivic, const float* __restrict__ sb,
                        const float* __restrict__ gg,   const float* __restrict__ fS,
                        const float* __restrict__ fd,   float* __restrict__ W)
{
    int idx = blockIdx.x * 256 + threadIdx.x;
    int r = idx >> 11, c = idx & (NN - 1);
    float hv0 = hv[0], hv1 = hv[1], sv0 = sv[0], dv0 = dv[0];
    float g0 = gg[0], fS0 = fS[0], fd0 = fd[0];

    float val = 0.f;
    #pragma unroll
    for (int t = 0; t < 2; ++t) {
        int rr = t ? c : r;
        int cc = t ? r : c;
        int e  = rr * NN + cc;
        float v = hv0 * hop[e] - hop[NN*NN + e] + hv1 * hop[2*NN*NN + e]
                + sv0 * swm[e] + dv0 * dwm[e];
        int i = rr & (LL - 1), j = cc & (LL - 1);
        float px = 0.f, py = 0.f;
        float s = sb[i * LL + j];
        int n0 = ivic[i*4+0], n1 = ivic[i*4+1], n2 = ivic[i*4+2], n3 = ivic[i*4+3];
        if (j == n1 || j == n3) px = (X[j] - X[i]) * s;
        if (j == n0 || j == n2) py = (Y[j] - Y[i]) * s;
        float P = px + py, Mm = px - py;
        bool rlo = rr < LL, clo = cc < LL;
        if (rlo && clo)        v += g0 * P;
        else if (!rlo && !clo) v -= g0 * P;
        else                   v += fS0 * P + fd0 * Mm;
        val += 0.5f * v;
    }
    W[idx] = val;
}

// --------------------- power iteration for spectral radius ------------------
__global__ void powv_init(float* v)
{
    int i = blockIdx.x * 256 + threadIdx.x;
    if (i < NN) {
        unsigned h = (unsigned)i * 2654435761u;
        h ^= h >> 13; h *= 2246822519u; h ^= h >> 16;
        v[i] = ((h >> 8) * (1.0f / 16777216.f)) - 0.5f;
    }
}

__global__ void matvec(const float* __restrict__ W, const float* __restrict__ vin,
                       float* __restrict__ vout, double* accslot)
{
    __shared__ float red[256];
    int row = blockIdx.x, tid = threadIdx.x;
    const float* wr = W + (size_t)row * NN;
    float s = 0.f;
    for (int j = tid; j < NN; j += 256) s += wr[j] * vin[j];
    red[tid] = s; __syncthreads();
    for (int off = 128; off; off >>= 1) { if (tid < off) red[tid] += red[tid + off]; __syncthreads(); }
    if (tid == 0) { float y = red[0]; vout[row] = y; atomicAdd(accslot, (double)y * (double)y); }
}

__global__ void add_shift(float* W, const double* acc)
{
    int i = blockIdx.x * 256 + threadIdx.x;
    if (i < NN) {
        double n1 = acc[8 + PITER - 1], n0 = acc[8 + PITER - 2];
        float rho = (float)sqrt(n1 / (n0 > 0.0 ? n0 : 1.0));
        W[(size_t)i * NN + i] += 1.45f * rho;
    }
}

// ------------------- blocked Jacobi helpers ---------------------------------
__device__ __forceinline__ void pair_groups(int pair, int r, int& gp, int& gq)
{
    if (pair == 0) gp = 0;
    else { int t1 = pair - 1 + r; if (t1 >= 63) t1 -= 63; gp = 1 + t1; }
    int t2 = 62 - pair + r; if (t2 >= 63) t2 -= 63; gq = 1 + t2;
}

// Phase A: partial Gram of the 64-column pair over a 128-row chunk.
// grid 512 = 32 pairs x 16 chunks.
__global__ __launch_bounds__(256) void jac_gram(const float* __restrict__ W,
                                                float* __restrict__ Gpart, int r)
{
    __shared__ float TT[64][132];
    int pair = blockIdx.x >> 4, chunk = blockIdx.x & 15;
    int tid = threadIdx.x;
    int gp, gq; pair_groups(pair, r, gp, gq);
    int r0 = chunk * 128;

    for (int u = tid; u < 64 * 32; u += 256) {
        int c = u >> 5, r4 = (u & 31) << 2;
        int col = (c < 32) ? gp * 32 + c : gq * 32 + (c - 32);
        float4 v = *(const float4*)(W + (size_t)col * NN + r0 + r4);
        *(float4*)&TT[c][r4] = v;
    }
    __syncthreads();

    int ti = tid >> 4, tj = tid & 15;
    float acc[4][4] = {};
    for (int r4 = 0; r4 < 128; r4 += 4) {
        float a[4][4], b[4][4];
        #pragma unroll
        for (int m = 0; m < 4; ++m) *(float4*)a[m] = *(const float4*)&TT[ti + 16*m][r4];
        #pragma unroll
        for (int n = 0; n < 4; ++n) *(float4*)b[n] = *(const float4*)&TT[tj + 16*n][r4];
        #pragma unroll
        for (int m = 0; m < 4; ++m)
            #pragma unroll
            for (int n = 0; n < 4; ++n)
                #pragma unroll
                for (int k = 0; k < 4; ++k)
                    acc[m][n] += a[m][k] * b[n][k];
    }
    float* gout = Gpart + ((size_t)(pair << 4) + chunk) * 4096;
    #pragma unroll
    for (int m = 0; m < 4; ++m)
        #pragma unroll
        for (int n = 0; n < 4; ++n)
            gout[(ti + 16*m) * 64 + (tj + 16*n)] = acc[m][n];
}

// Phase B: reduce partial Grams; block-skip check; one inner sweep (<=63 rounds,
// mid-sweep break when all rotations go identity) of two-sided Jacobi via
// one-pass 2x2-block J^T S J updates; accumulate V. grid 32, 512 threads.
__global__ __launch_bounds__(512) void jac_solve(const float* __restrict__ Gpart,
                                                 float* __restrict__ Vbuf,
                                                 int* __restrict__ flags, int r)
{
    __shared__ float S[64][65];
    __shared__ float Vl[64][65];
    __shared__ float csC[32], csS[32];
    __shared__ int   pk[32], qk[32];
    __shared__ int   active;
    __shared__ int   nact[2];      // double-buffered "any non-identity rotation this round"
    int pair = blockIdx.x, tid = threadIdx.x;
    if (tid == 0) active = 0;
    if (tid < 2) nact[tid] = 0;

    for (int e4 = tid; e4 < 1024; e4 += 512) {
        float4 s = {0.f, 0.f, 0.f, 0.f};
        #pragma unroll
        for (int ch = 0; ch < 16; ++ch) {
            const float4* gp = (const float4*)(Gpart + ((size_t)(pair * 16 + ch)) * 4096);
            float4 v = gp[e4];
            s.x += v.x; s.y += v.y; s.z += v.z; s.w += v.w;
        }
        int i = e4 >> 4, j0 = (e4 & 15) << 2;
        S[i][j0] = s.x; S[i][j0+1] = s.y; S[i][j0+2] = s.z; S[i][j0+3] = s.w;
        Vl[i][j0]   = (i == j0)     ? 1.f : 0.f;
        Vl[i][j0+1] = (i == j0 + 1) ? 1.f : 0.f;
        Vl[i][j0+2] = (i == j0 + 2) ? 1.f : 0.f;
        Vl[i][j0+3] = (i == j0 + 3) ? 1.f : 0.f;
    }
    __syncthreads();

    // block-skip: if every off-diagonal is below threshold, V = I.
    int loc = 0;
    for (int e = tid; e < 4096; e += 512) {
        int i = e >> 6, j = e & 63;
        if (i < j) {
            float o = S[i][j];
            if (o * o > JTAU * S[i][i] * S[j][j]) loc = 1;
        }
    }
    if (loc) active = 1;          // benign race: only ever set to 1
    __syncthreads();
    if (!active) { if (tid == 0) flags[pair] = 1; return; }
    if (tid == 0) flags[pair] = 0;

    for (int r2 = 0; r2 < 63; ++r2) {
        if (tid < 32) {
            int k = tid, p, q;
            if (k == 0) p = 0;
            else { int t1 = k - 1 + r2; if (t1 >= 63) t1 -= 63; p = 1 + t1; }
            int t2 = 62 - k + r2; if (t2 >= 63) t2 -= 63; q = 1 + t2;
            float app = S[p][p], aqq = S[q][q], apq = S[p][q];
            float c = 1.f, s = 0.f;
            if (apq * apq > JTAU * app * aqq) {
                float tau = (aqq - app) / (2.f * apq);
                float t = (tau >= 0.f ? 1.f : -1.f) / (fabsf(tau) + sqrtf(1.f + tau * tau));
                c = 1.f / sqrtf(1.f + t * t);
                s = t * c;
                nact[r2 & 1] = 1;     // benign multi-writer, same value
            }
            csC[k] = c; csS[k] = s; pk[k] = p; qk[k] = q;
        }
        if (tid == 256) nact[(r2 + 1) & 1] = 0;   // reset other slot for next round
        __syncthreads();
        if (!nact[r2 & 1]) break;    // uniform: all rotations identity -> done
        // one-pass S <- J^T S J over disjoint 2x2 blocks
        for (int u = tid; u < 1024; u += 512) {
            int ki = u >> 5, kj = u & 31;
            float si_ = csS[ki], sj_ = csS[kj];
            if (si_ == 0.f && sj_ == 0.f) continue;
            float ci_ = csC[ki], cj_ = csC[kj];
            int pi = pk[ki], qi = qk[ki], pj = pk[kj], qj = qk[kj];
            float a  = S[pi][pj], b  = S[pi][qj];
            float c2 = S[qi][pj], d  = S[qi][qj];
            float a1 = cj_ * a  - sj_ * b,  b1 = sj_ * a  + cj_ * b;
            float c1 = cj_ * c2 - sj_ * d,  d1 = sj_ * c2 + cj_ * d;
            S[pi][pj] = ci_ * a1 - si_ * c1;
            S[qi][pj] = si_ * a1 + ci_ * c1;
            S[pi][qj] = ci_ * b1 - si_ * d1;
            S[qi][qj] = si_ * b1 + ci_ * d1;
        }
        // V <- V * J
        for (int u = tid; u < 2048; u += 512) {
            int rr = u >> 5, k = u & 31;
            float s_ = csS[k];
            if (s_ == 0.f) continue;
            float c_ = csC[k];
            int p = pk[k], q = qk[k];
            float vp = Vl[rr][p], vq = Vl[rr][q];
            Vl[rr][p] = c_ * vp - s_ * vq;
            Vl[rr][q] = s_ * vp + c_ * vq;
        }
        __syncthreads();
    }
    for (int e4 = tid; e4 < 1024; e4 += 512) {
        int i = e4 >> 4, j0 = (e4 & 15) << 2;
        float4 v = { Vl[i][j0], Vl[i][j0+1], Vl[i][j0+2], Vl[i][j0+3] };
        ((float4*)(Vbuf + (size_t)pair * 4096))[e4] = v;
    }
}

// Phase C: W_pair <- W_pair * V over a 128-row chunk; early-out on flag. grid 512.
__global__ __launch_bounds__(256) void jac_apply(float* __restrict__ W,
                                                 const float* __restrict__ Vbuf,
                                                 const int* __restrict__ flags, int r)
{
    __shared__ float TT[64][132];
    __shared__ float Vs[64][64];
    int pair = blockIdx.x >> 4, chunk = blockIdx.x & 15;
    if (flags[pair]) return;       // V == I, columns unchanged
    int tid = threadIdx.x;
    int gp, gq; pair_groups(pair, r, gp, gq);
    int r0 = chunk * 128;

    for (int u = tid; u < 64 * 32; u += 256) {
        int c = u >> 5, r4 = (u & 31) << 2;
        int col = (c < 32) ? gp * 32 + c : gq * 32 + (c - 32);
        float4 v = *(const float4*)(W + (size_t)col * NN + r0 + r4);
        *(float4*)&TT[c][r4] = v;
    }
    for (int e4 = tid; e4 < 1024; e4 += 256) {
        float4 v = ((const float4*)(Vbuf + (size_t)pair * 4096))[e4];
        int i = e4 >> 4, j0 = (e4 & 15) << 2;
        Vs[i][j0] = v.x; Vs[i][j0+1] = v.y; Vs[i][j0+2] = v.z; Vs[i][j0+3] = v.w;
    }
    __syncthreads();

    int rt = tid >> 3, ct = tid & 7;
    int rr0 = rt << 2, c20 = ct << 3;
    float acc[4][8] = {};
    for (int c = 0; c < 64; ++c) {
        float a[4], b[8];
        *(float4*)a     = *(const float4*)&TT[c][rr0];
        *(float4*)b     = *(const float4*)&Vs[c][c20];
        *(float4*)&b[4] = *(const float4*)&Vs[c][c20 + 4];
        #pragma unroll
        for (int i = 0; i < 4; ++i)
            #pragma unroll
            for (int j = 0; j < 8; ++j)
                acc[i][j] += a[i] * b[j];
    }
    #pragma unroll
    for (int j = 0; j < 8; ++j) {
        int cc = c20 + j;
        int col = (cc < 32) ? gp * 32 + cc : gq * 32 + (cc - 32);
        float4 v = { acc[0][j], acc[1][j], acc[2][j], acc[3][j] };
        *(float4*)(W + (size_t)col * NN + r0 + rr0) = v;
    }
}

// --------------------- norms, selection, gather -----------------------------
__global__ void colnorms(const float* __restrict__ W, float* __restrict__ sig2)
{
    __shared__ float red[256];
    int col = blockIdx.x, tid = threadIdx.x;
    const float* c = W + (size_t)col * NN;
    float s = 0.f;
    for (int e = tid; e < NN; e += 256) s += c[e] * c[e];
    red[tid] = s; __syncthreads();
    for (int off = 128; off; off >>= 1) { if (tid < off) red[tid] += red[tid + off]; __syncthreads(); }
    if (tid == 0) sig2[col] = red[0];
}

__global__ void select_k(const float* __restrict__ sig2, int* __restrict__ sel)
{
    int i = blockIdx.x * 256 + threadIdx.x;
    if (i >= NN) return;
    float di = sig2[i]; int rank = 0;
    for (int j = 0; j < NN; ++j) {
        float dj = sig2[j];
        rank += (dj < di) || (dj == di && j < i);
    }
    if (rank < LL) sel[rank] = i;
}

__global__ void gather_M(const float* __restrict__ W, const float* __restrict__ sig2,
                         const int* __restrict__ sel, const int* __restrict__ occ,
                         float* __restrict__ Mt)
{
    int idx = blockIdx.x * 256 + threadIdx.x;
    int b = idx >> 10, a = idx & (LL - 1);
    int col = sel[b];
    float rn = 1.f / sqrtf(sig2[col]);
    Mt[(size_t)b * LL + a] = W[(size_t)col * NN + occ[a]] * rn;
}

// G = Mt^T * Mt in fp64 (= M M^T)
__global__ void gram(const float* __restrict__ Mt, double* __restrict__ G)
{
    __shared__ float As[32][17], Bs[32][17];
    int t = threadIdx.x;
    int tx = t & 15, ty = t >> 4;
    int a0 = blockIdx.y * 16, c0 = blockIdx.x * 16;
    double s = 0.0;
    for (int kb = 0; kb < LL; kb += 32) {
        for (int u = t; u < 32 * 16; u += 256) {
            int kr = u >> 4, i = u & 15;
            As[kr][i] = Mt[(size_t)(kb + kr) * LL + a0 + i];
            Bs[kr][i] = Mt[(size_t)(kb + kr) * LL + c0 + i];
        }
        __syncthreads();
        #pragma unroll 8
        for (int k2 = 0; k2 < 32; ++k2)
            s += (double)As[k2][ty] * (double)Bs[k2][tx];
        __syncthreads();
    }
    G[(size_t)(a0 + ty) * LL + (c0 + tx)] = s;
}

// --------------------- blocked fp64 Cholesky (panel 64) ---------------------
__global__ void chol_panel(double* __restrict__ G, int k0, double* __restrict__ acc)
{
    __shared__ double Ld[64][65];
    __shared__ double sinv;
    int tid = threadIdx.x;
    for (int u = tid; u < 4096; u += 256)
        Ld[u >> 6][u & 63] = G[(size_t)(k0 + (u >> 6)) * LL + k0 + (u & 63)];
    __syncthreads();
    double lsum = 0.0;
    for (int c = 0; c < 64; ++c) {
        if (tid == 0) {
            double d = Ld[c][c]; d = d > 1e-300 ? d : 1e-300;
            double sd = sqrt(d); lsum += log(sd);
            Ld[c][c] = sd; sinv = 1.0 / sd;
        }
        __syncthreads();
        if (tid < 63 - c) Ld[c + 1 + tid][c] *= sinv;
        __syncthreads();
        for (int u = tid; u < 4096; u += 256) {
            int rr = u >> 6, cc = u & 63;
            if (rr > c && cc > c) Ld[rr][cc] -= Ld[rr][c] * Ld[cc][c];
        }
        __syncthreads();
    }
    for (int u = tid; u < 4096; u += 256)
        G[(size_t)(k0 + (u >> 6)) * LL + k0 + (u & 63)] = Ld[u >> 6][u & 63];
    if (tid == 0) atomicAdd(acc + 1, lsum);
}

__global__ void chol_trsm(double* __restrict__ G, int k0)
{
    __shared__ double L11[64][65];
    __shared__ double Rt[32][65];
    int tid = threadIdx.x;
    int rbase = k0 + 64 + blockIdx.x * 32;
    for (int u = tid; u < 4096; u += 256)
        L11[u >> 6][u & 63] = G[(size_t)(k0 + (u >> 6)) * LL + k0 + (u & 63)];
    for (int u = tid; u < 2048; u += 256)
        Rt[u >> 6][u & 63] = G[(size_t)(rbase + (u >> 6)) * LL + k0 + (u & 63)];
    __syncthreads();
    for (int c = 0; c < 64; ++c) {
        if (tid < 32) Rt[tid][c] *= 1.0 / L11[c][c];
        __syncthreads();
        for (int u = tid; u < 2048; u += 256) {
            int rr = u >> 6, cc = u & 63;
            if (cc > c) Rt[rr][cc] -= Rt[rr][c] * L11[cc][c];
        }
        __syncthreads();
    }
    for (int u = tid; u < 2048; u += 256)
        G[(size_t)(rbase + (u >> 6)) * LL + k0 + (u & 63)] = Rt[u >> 6][u & 63];
}

__global__ void chol_syrk(double* __restrict__ G, int k0)
{
    __shared__ double At[64][32];
    __shared__ double Bt[64][32];
    int tid = threadIdx.x;
    int r0g = k0 + 64 + blockIdx.y * 64;
    int c0g = k0 + 64 + blockIdx.x * 64;
    int i0 = (tid >> 4) << 2, j0 = (tid & 15) << 2;
    double acc[4][4] = {};
    for (int kh = 0; kh < 2; ++kh) {
        for (int u = tid; u < 2048; u += 256) {
            int i = u >> 5, c = u & 31;
            At[i][c] = G[(size_t)(r0g + i) * LL + k0 + kh * 32 + c];
            Bt[i][c] = G[(size_t)(c0g + i) * LL + k0 + kh * 32 + c];
        }
        __syncthreads();
        for (int c = 0; c < 32; ++c) {
            int cr = (c + tid) & 31;
            double a[4], b[4];
            #pragma unroll
            for (int i = 0; i < 4; ++i) a[i] = At[i0 + i][cr];
            #pragma unroll
            for (int j = 0; j < 4; ++j) b[j] = Bt[j0 + j][cr];
            #pragma unroll
            for (int i = 0; i < 4; ++i)
                #pragma unroll
                for (int j = 0; j < 4; ++j)
                    acc[i][j] += a[i] * b[j];
        }
        __syncthreads();
    }
    #pragma unroll
    for (int i = 0; i < 4; ++i)
        #pragma unroll
        for (int j = 0; j < 4; ++j) {
            size_t e = (size_t)(r0g + i0 + i) * LL + c0g + j0 + j;
            G[e] -= acc[i][j];
        }
}

// --------- all O(L^2) circulant quadratic forms + coherent terms ------------
__global__ void pair_sums(const float* __restrict__ Sz,  const float* __restrict__ X,
                          const float* __restrict__ Y,
                          const float* __restrict__ Jsp, const float* __restrict__ JXel,
                          const float* __restrict__ JYel,const float* __restrict__ pXX,
                          const float* __restrict__ pXY, const float* __restrict__ pYY,
                          const float* __restrict__ sb,  const float* __restrict__ stx,
                          const float* __restrict__ sty,
                          const float* __restrict__ zx,  const float* __restrict__ zy,
                          const float* __restrict__ xr,  const float* __restrict__ yr,
                          double* __restrict__ acc)
{
    __shared__ float tS[289], tXe[289], tYe[289], tXX[289], tXY[289], tYY[289];
    __shared__ double red[256];
    int tid = threadIdx.x;
    for (int u = tid; u < 289; u += 256) {
        tS[u]  = (u < 288) ? Jsp[u] : 0.f;
        tXX[u] = (u < 288) ? pXX[u] : 0.f;
        tXY[u] = (u < 288) ? pXY[u] : 0.f;
        tYY[u] = (u < 288) ? pYY[u] : 0.f;
        tXe[u] = (u >= 1 && u < 288) ? JXel[u - 1] : 0.f;
        tYe[u] = (u >= 1 && u < 288) ? JYel[u - 1] : 0.f;
    }
    __syncthreads();
    int idx = blockIdx.x * 256 + tid;
    int i = idx >> 10, j = idx & (LL - 1);
    int xi = i >> 5, yi = i & 31, xj = j >> 5, yj = j & 31;
    int dx = (xj - xi) & 31, dy = (yj - yi) & 31;
    int rx = (dx <= 16) ? dx : 32 - dx;
    int ry = (dy <= 16) ? dy : 32 - dy;
    int ti = rx * 17 + ry;
    float si = Sz[i], sj = Sz[j];
    float Xi = X[i], Xj = X[j], Yi = Y[i], Yj = Y[j];
    float sbij = sb[i * LL + j];
    double sum = (double)(si * sj) * (double)tS[ti];
    sum += (double)(Xi * Xj) * (double)tXX[ti];
    sum += (double)(Yi * Xj + Xi * Yj) * (double)tXY[ti];
    sum += (double)(Yi * Yj) * (double)tYY[ti];
    sum += (double)(si * sj * sbij) *
           ((double)tXe[ti] * (double)(Xi - Xj) + (double)tYe[ti] * (double)(Yi - Yj));
    if (i == j) {
        float ex = Xi - zx[0] * stx[i];
        float ey = Yi - zy[0] * sty[i];
        sum -= 0.5 * (double)xr[0] * ex * ex + 0.5 * (double)yr[0] * ey * ey;
    }
    red[tid] = sum; __syncthreads();
    for (int off = 128; off; off >>= 1) { if (tid < off) red[tid] += red[tid + off]; __syncthreads(); }
    if (tid == 0) atomicAdd(&acc[0], red[0]);
}

__global__ void finalize(const double* __restrict__ acc, float* __restrict__ out)
{
    out[0] = (float)(acc[0] + acc[1]);
}

// ---------------------------------------------------------------------------
extern "C" void kernel_launch(void* const* d_in, const int* in_sizes, int n_in,
                              void* d_out, int out_size, void* d_ws, size_t ws_size,
                              hipStream_t stream)
{
    const int*   occ  = (const int*)  d_in[0];
    const float* Sz   = (const float*)d_in[2];
    const float* X    = (const float*)d_in[3];
    const float* Y    = (const float*)d_in[4];
    const float* hv   = (const float*)d_in[5];
    const float* sv   = (const float*)d_in[6];
    const float* dv   = (const float*)d_in[7];
    const float* Jsp  = (const float*)d_in[8];
    const float* JXel = (const float*)d_in[9];
    const float* JYel = (const float*)d_in[10];
    const float* pXX  = (const float*)d_in[11];
    const float* pXY  = (const float*)d_in[12];
    const float* pYY  = (const float*)d_in[13];
    const float* g    = (const float*)d_in[14];
    const float* fS   = (const float*)d_in[15];
    const float* fd   = (const float*)d_in[16];
    const float* zx   = (const float*)d_in[17];
    const float* zy   = (const float*)d_in[18];
    const float* xr   = (const float*)d_in[19];
    const float* yr   = (const float*)d_in[20];
    const float* hop  = (const float*)d_in[21];
    const float* swm  = (const float*)d_in[22];
    const float* dwm  = (const float*)d_in[23];
    const int*   ivic = (const int*)  d_in[24];
    const float* sb   = (const float*)d_in[25];
    const float* stx  = (const float*)d_in[26];
    const float* sty  = (const float*)d_in[27];
    float* out = (float*)d_out;

    char* ws = (char*)d_ws;
    float*  W    = (float*) (ws + 0);           // 16.78 MB
    float*  v0   = (float*) (ws + 16777216);    // 8 KB
    float*  v1   = (float*) (ws + 16785408);    // 4 KB used
    int*    flags= (int*)   (ws + 16789504);    // 128 B
    float*  sig2 = (float*) (ws + 16793600);
    int*    sel  = (int*)   (ws + 16801792);
    float*  Mt   = (float*) (ws + 16805888);    // 4 MB; first 512KB doubles as Vbuf during Jacobi
    double* G    = (double*)(ws + 21000192);    // 8 MB fp64 Gram; doubles as Gpart (fp32) during Jacobi
    double* acc  = (double*)(ws + 29388800);
    float*  Vbuf  = Mt;
    float*  Gpart = (float*)G;

    hipMemsetAsync(acc, 0, 256, stream);
    build_H<<<NN * NN / 256, 256, 0, stream>>>(hop, swm, dwm, hv, sv, dv, X, Y,
                                               ivic, sb, g, fS, fd, W);
    powv_init<<<8, 256, 0, stream>>>(v0);
    for (int it = 0; it < PITER; ++it) {
        const float* vin = (it & 1) ? v1 : v0;
        float* vout = (it & 1) ? v0 : v1;
        matvec<<<NN, 256, 0, stream>>>(W, vin, vout, acc + 8 + it);
    }
    add_shift<<<8, 256, 0, stream>>>(W, acc);

    for (int sw = 0; sw < NSWB; ++sw)
        for (int r = 0; r < 63; ++r) {
            jac_gram <<<512, 256, 0, stream>>>(W, Gpart, r);
            jac_solve<<<32,  512, 0, stream>>>(Gpart, Vbuf, flags, r);
            jac_apply<<<512, 256, 0, stream>>>(W, Vbuf, flags, r);
        }

    colnorms<<<NN, 256, 0, stream>>>(W, sig2);
    select_k<<<8, 256, 0, stream>>>(sig2, sel);
    gather_M<<<4096, 256, 0, stream>>>(W, sig2, sel, occ, Mt);
    gram<<<dim3(64, 64), 256, 0, stream>>>(Mt, G);

    for (int s = 0; s < 16; ++s) {
        int k0 = s * 64;
        chol_panel<<<1, 256, 0, stream>>>(G, k0, acc);
        int nrows = LL - k0 - 64;
        if (nrows > 0) {
            chol_trsm<<<nrows / 32, 256, 0, stream>>>(G, k0);
            chol_syrk<<<dim3(nrows / 64, nrows / 64), 256, 0, stream>>>(G, k0);
        }
    }

    pair_sums<<<4096, 256, 0, stream>>>(Sz, X, Y, Jsp, JXel, JYel, pXX, pXY, pYY,
                                        sb, stx, sty, zx, zy, xr, yr, acc);
    finalize<<<1, 1, 0, stream>>>(acc, out);
}

// Round 5
// 67251.855 us; speedup vs baseline: 1.1584x; 1.1584x over previous
//
#include <hip/hip_runtime.h>
#include <math.h>

#define NN 2048   // 2L
#define LL 1024   // L
#define NSWB 8    // blocked Jacobi sweeps (converged sweeps collapse to launch cost)
#define PITER 10  // power iterations for spectral radius
#define JTAU 1e-8f   // relative off^2 threshold: |apq|_rel < 1e-4 -> identity.
                     // apply-GEMM noise random-walks to ~1.3e-5 rel over 600 rounds,
                     // so 1e-4 is ~8x above the floor and skips genuinely fire
                     // (R3's 1e-11 and R4's 1e-10 sat at/below the floor; never fired)
#define STREAK_FULL 2016   // 63 rounds x 32 pairs all-skip = one clean sweep

// gctl layout (ints, zeroed at launch): [0]=gconv [1]=streak [2..65]=clean[64]

// ---------------------------------------------------------------------------
// Build W = (H0 + H0^T)/2  (eigh symmetrizes input; phonon part asymmetric).
// Column p contiguous at W + p*NN (symmetric).
// ---------------------------------------------------------------------------
__global__ void build_H(const float* __restrict__ hop,  const float* __restrict__ swm,
                        const float* __restrict__ dwm,  const float* __restrict__ hv,
                        const float* __restrict__ sv,   const float* __restrict__ dv,
                        const float* __restrict__ X,    const float* __restrict__ Y,
                        const int*   __restrict__ ivic, const float* __restrict__ sb,
                        const float* __restrict__ gg,   const float* __restrict__ fS,
                        const float* __restrict__ fd,   float* __restrict__ W)
{
    int idx = blockIdx.x * 256 + threadIdx.x;
    int r = idx >> 11, c = idx & (NN - 1);
    float hv0 = hv[0], hv1 = hv[1], sv0 = sv[0], dv0 = dv[0];
    float g0 = gg[0], fS0 = fS[0], fd0 = fd[0];

    float val = 0.f;
    #pragma unroll
    for (int t = 0; t < 2; ++t) {
        int rr = t ? c : r;
        int cc = t ? r : c;
        int e  = rr * NN + cc;
        float v = hv0 * hop[e] - hop[NN*NN + e] + hv1 * hop[2*NN*NN + e]
                + sv0 * swm[e] + dv0 * dwm[e];
        int i = rr & (LL - 1), j = cc & (LL - 1);
        float px = 0.f, py = 0.f;
        float s = sb[i * LL + j];
        int n0 = ivic[i*4+0], n1 = ivic[i*4+1], n2 = ivic[i*4+2], n3 = ivic[i*4+3];
        if (j == n1 || j == n3) px = (X[j] - X[i]) * s;
        if (j == n0 || j == n2) py = (Y[j] - Y[i]) * s;
        float P = px + py, Mm = px - py;
        bool rlo = rr < LL, clo = cc < LL;
        if (rlo && clo)        v += g0 * P;
        else if (!rlo && !clo) v -= g0 * P;
        else                   v += fS0 * P + fd0 * Mm;
        val += 0.5f * v;
    }
    W[idx] = val;
}

// --------------------- power iteration for spectral radius ------------------
__global__ void powv_init(float* v)
{
    int i = blockIdx.x * 256 + threadIdx.x;
    if (i < NN) {
        unsigned h = (unsigned)i * 2654435761u;
        h ^= h >> 13; h *= 2246822519u; h ^= h >> 16;
        v[i] = ((h >> 8) * (1.0f / 16777216.f)) - 0.5f;
    }
}

__global__ void matvec(const float* __restrict__ W, const float* __restrict__ vin,
                       float* __restrict__ vout, double* accslot)
{
    __shared__ float red[256];
    int row = blockIdx.x, tid = threadIdx.x;
    const float* wr = W + (size_t)row * NN;
    float s = 0.f;
    for (int j = tid; j < NN; j += 256) s += wr[j] * vin[j];
    red[tid] = s; __syncthreads();
    for (int off = 128; off; off >>= 1) { if (tid < off) red[tid] += red[tid + off]; __syncthreads(); }
    if (tid == 0) { float y = red[0]; vout[row] = y; atomicAdd(accslot, (double)y * (double)y); }
}

__global__ void add_shift(float* W, const double* acc)
{
    int i = blockIdx.x * 256 + threadIdx.x;
    if (i < NN) {
        double n1 = acc[8 + PITER - 1], n0 = acc[8 + PITER - 2];
        float rho = (float)sqrt(n1 / (n0 > 0.0 ? n0 : 1.0));
        W[(size_t)i * NN + i] += 1.45f * rho;
    }
}

// ------------------- blocked Jacobi helpers ---------------------------------
__device__ __forceinline__ void pair_groups(int pair, int r, int& gp, int& gq)
{
    if (pair == 0) gp = 0;
    else { int t1 = pair - 1 + r; if (t1 >= 63) t1 -= 63; gp = 1 + t1; }
    int t2 = 62 - pair + r; if (t2 >= 63) t2 -= 63; gq = 1 + t2;
}

// Phase A: partial Gram of the 64-column pair over a 128-row chunk.
// grid 512 = 32 pairs x 16 chunks. Skips when globally converged or both
// groups are "clean" (full sweep of identity pairings).
__global__ __launch_bounds__(256) void jac_gram(const float* __restrict__ W,
                                                float* __restrict__ Gpart,
                                                const int* __restrict__ gctl, int r)
{
    if (gctl[0]) return;                      // globally converged
    __shared__ float TT[64][132];
    int pair = blockIdx.x >> 4, chunk = blockIdx.x & 15;
    int tid = threadIdx.x;
    int gp, gq; pair_groups(pair, r, gp, gq);
    if (gctl[2 + gp] >= 63 && gctl[2 + gq] >= 63) return;   // pair provably diagonal
    int r0 = chunk * 128;

    for (int u = tid; u < 64 * 32; u += 256) {
        int c = u >> 5, r4 = (u & 31) << 2;
        int col = (c < 32) ? gp * 32 + c : gq * 32 + (c - 32);
        float4 v = *(const float4*)(W + (size_t)col * NN + r0 + r4);
        *(float4*)&TT[c][r4] = v;
    }
    __syncthreads();

    int ti = tid >> 4, tj = tid & 15;
    float acc[4][4] = {};
    for (int r4 = 0; r4 < 128; r4 += 4) {
        float a[4][4], b[4][4];
        #pragma unroll
        for (int m = 0; m < 4; ++m) *(float4*)a[m] = *(const float4*)&TT[ti + 16*m][r4];
        #pragma unroll
        for (int n = 0; n < 4; ++n) *(float4*)b[n] = *(const float4*)&TT[tj + 16*n][r4];
        #pragma unroll
        for (int m = 0; m < 4; ++m)
            #pragma unroll
            for (int n = 0; n < 4; ++n)
                #pragma unroll
                for (int k = 0; k < 4; ++k)
                    acc[m][n] += a[m][k] * b[n][k];
    }
    float* gout = Gpart + ((size_t)(pair << 4) + chunk) * 4096;
    #pragma unroll
    for (int m = 0; m < 4; ++m)
        #pragma unroll
        for (int n = 0; n < 4; ++n)
            gout[(ti + 16*m) * 64 + (tj + 16*n)] = acc[m][n];
}

// Phase B: reduce partial Grams; hint/block-skip; one inner sweep (<=63 rounds,
// mid-sweep break) of two-sided Jacobi via one-pass 2x2-block J^T S J updates;
// accumulate V. grid 32 (one block per pair), 512 threads.
__global__ __launch_bounds__(512) void jac_solve(const float* __restrict__ Gpart,
                                                 float* __restrict__ Vbuf,
                                                 int* __restrict__ flags,
                                                 int* __restrict__ gctl, int r)
{
    __shared__ float S[64][65];
    __shared__ float Vl[64][65];
    __shared__ float csC[32], csS[32];
    __shared__ int   pk[32], qk[32];
    __shared__ int   active;
    __shared__ int   nact[2];
    int pair = blockIdx.x, tid = threadIdx.x;

    if (gctl[0]) return;                      // globally converged
    int gp, gq; pair_groups(pair, r, gp, gq);
    int hint = (gctl[2 + gp] >= 63 && gctl[2 + gq] >= 63);
    if (hint) {
        if (tid == 0) {
            flags[pair] = 1;
            gctl[2 + gp] += 1;                // single writer per group per round
            gctl[2 + gq] += 1;
            int old = atomicAdd(&gctl[1], 1);
            if (old + 1 >= STREAK_FULL) gctl[0] = 1;
        }
        return;
    }

    if (tid == 0) active = 0;
    if (tid < 2) nact[tid] = 0;

    for (int e4 = tid; e4 < 1024; e4 += 512) {
        float4 s = {0.f, 0.f, 0.f, 0.f};
        #pragma unroll
        for (int ch = 0; ch < 16; ++ch) {
            const float4* gpt = (const float4*)(Gpart + ((size_t)(pair * 16 + ch)) * 4096);
            float4 v = gpt[e4];
            s.x += v.x; s.y += v.y; s.z += v.z; s.w += v.w;
        }
        int i = e4 >> 4, j0 = (e4 & 15) << 2;
        S[i][j0] = s.x; S[i][j0+1] = s.y; S[i][j0+2] = s.z; S[i][j0+3] = s.w;
        Vl[i][j0]   = (i == j0)     ? 1.f : 0.f;
        Vl[i][j0+1] = (i == j0 + 1) ? 1.f : 0.f;
        Vl[i][j0+2] = (i == j0 + 2) ? 1.f : 0.f;
        Vl[i][j0+3] = (i == j0 + 3) ? 1.f : 0.f;
    }
    __syncthreads();

    // block-skip: if every off-diagonal is below threshold, V = I.
    int loc = 0;
    for (int e = tid; e < 4096; e += 512) {
        int i = e >> 6, j = e & 63;
        if (i < j) {
            float o = S[i][j];
            if (o * o > JTAU * S[i][i] * S[j][j]) loc = 1;
        }
    }
    if (loc) active = 1;          // benign race: only ever set to 1
    __syncthreads();
    if (!active) {
        if (tid == 0) {
            flags[pair] = 1;
            gctl[2 + gp] += 1;
            gctl[2 + gq] += 1;
            int old = atomicAdd(&gctl[1], 1);
            if (old + 1 >= STREAK_FULL) gctl[0] = 1;
        }
        return;
    }
    if (tid == 0) {
        flags[pair] = 0;
        gctl[2 + gp] = 0;
        gctl[2 + gq] = 0;
        atomicExch(&gctl[1], 0);
    }

    for (int r2 = 0; r2 < 63; ++r2) {
        if (tid < 32) {
            int k = tid, p, q;
            if (k == 0) p = 0;
            else { int t1 = k - 1 + r2; if (t1 >= 63) t1 -= 63; p = 1 + t1; }
            int t2 = 62 - k + r2; if (t2 >= 63) t2 -= 63; q = 1 + t2;
            float app = S[p][p], aqq = S[q][q], apq = S[p][q];
            float c = 1.f, s = 0.f;
            if (apq * apq > JTAU * app * aqq) {
                float tau = (aqq - app) / (2.f * apq);
                float t = (tau >= 0.f ? 1.f : -1.f) / (fabsf(tau) + sqrtf(1.f + tau * tau));
                c = 1.f / sqrtf(1.f + t * t);
                s = t * c;
                nact[r2 & 1] = 1;     // benign multi-writer, same value
            }
            csC[k] = c; csS[k] = s; pk[k] = p; qk[k] = q;
        }
        if (tid == 256) nact[(r2 + 1) & 1] = 0;
        __syncthreads();
        if (!nact[r2 & 1]) break;
        // one-pass S <- J^T S J over disjoint 2x2 blocks
        for (int u = tid; u < 1024; u += 512) {
            int ki = u >> 5, kj = u & 31;
            float si_ = csS[ki], sj_ = csS[kj];
            if (si_ == 0.f && sj_ == 0.f) continue;
            float ci_ = csC[ki], cj_ = csC[kj];
            int pi = pk[ki], qi = qk[ki], pj = pk[kj], qj = qk[kj];
            float a  = S[pi][pj], b  = S[pi][qj];
            float c2 = S[qi][pj], d  = S[qi][qj];
            float a1 = cj_ * a  - sj_ * b,  b1 = sj_ * a  + cj_ * b;
            float c1 = cj_ * c2 - sj_ * d,  d1 = sj_ * c2 + cj_ * d;
            S[pi][pj] = ci_ * a1 - si_ * c1;
            S[qi][pj] = si_ * a1 + ci_ * c1;
            S[pi][qj] = ci_ * b1 - si_ * d1;
            S[qi][qj] = si_ * b1 + ci_ * d1;
        }
        // V <- V * J
        for (int u = tid; u < 2048; u += 512) {
            int rr = u >> 5, k = u & 31;
            float s_ = csS[k];
            if (s_ == 0.f) continue;
            float c_ = csC[k];
            int p = pk[k], q = qk[k];
            float vp = Vl[rr][p], vq = Vl[rr][q];
            Vl[rr][p] = c_ * vp - s_ * vq;
            Vl[rr][q] = s_ * vp + c_ * vq;
        }
        __syncthreads();
    }
    for (int e4 = tid; e4 < 1024; e4 += 512) {
        int i = e4 >> 4, j0 = (e4 & 15) << 2;
        float4 v = { Vl[i][j0], Vl[i][j0+1], Vl[i][j0+2], Vl[i][j0+3] };
        ((float4*)(Vbuf + (size_t)pair * 4096))[e4] = v;
    }
}

// Phase C: W_pair <- W_pair * V over a 128-row chunk; early-out on flags/gconv.
__global__ __launch_bounds__(256) void jac_apply(float* __restrict__ W,
                                                 const float* __restrict__ Vbuf,
                                                 const int* __restrict__ flags,
                                                 const int* __restrict__ gctl, int r)
{
    if (gctl[0]) return;
    __shared__ float TT[64][132];
    __shared__ float Vs[64][64];
    int pair = blockIdx.x >> 4, chunk = blockIdx.x & 15;
    if (flags[pair]) return;       // V == I, columns unchanged
    int tid = threadIdx.x;
    int gp, gq; pair_groups(pair, r, gp, gq);
    int r0 = chunk * 128;

    for (int u = tid; u < 64 * 32; u += 256) {
        int c = u >> 5, r4 = (u & 31) << 2;
        int col = (c < 32) ? gp * 32 + c : gq * 32 + (c - 32);
        float4 v = *(const float4*)(W + (size_t)col * NN + r0 + r4);
        *(float4*)&TT[c][r4] = v;
    }
    for (int e4 = tid; e4 < 1024; e4 += 256) {
        float4 v = ((const float4*)(Vbuf + (size_t)pair * 4096))[e4];
        int i = e4 >> 4, j0 = (e4 & 15) << 2;
        Vs[i][j0] = v.x; Vs[i][j0+1] = v.y; Vs[i][j0+2] = v.z; Vs[i][j0+3] = v.w;
    }
    __syncthreads();

    int rt = tid >> 3, ct = tid & 7;
    int rr0 = rt << 2, c20 = ct << 3;
    float acc[4][8] = {};
    for (int c = 0; c < 64; ++c) {
        float a[4], b[8];
        *(float4*)a     = *(const float4*)&TT[c][rr0];
        *(float4*)b     = *(const float4*)&Vs[c][c20];
        *(float4*)&b[4] = *(const float4*)&Vs[c][c20 + 4];
        #pragma unroll
        for (int i = 0; i < 4; ++i)
            #pragma unroll
            for (int j = 0; j < 8; ++j)
                acc[i][j] += a[i] * b[j];
    }
    #pragma unroll
    for (int j = 0; j < 8; ++j) {
        int cc = c20 + j;
        int col = (cc < 32) ? gp * 32 + cc : gq * 32 + (cc - 32);
        float4 v = { acc[0][j], acc[1][j], acc[2][j], acc[3][j] };
        *(float4*)(W + (size_t)col * NN + r0 + rr0) = v;
    }
}

// --------------------- norms, selection, gather -----------------------------
__global__ void colnorms(const float* __restrict__ W, float* __restrict__ sig2)
{
    __shared__ float red[256];
    int col = blockIdx.x, tid = threadIdx.x;
    const float* c = W + (size_t)col * NN;
    float s = 0.f;
    for (int e = tid; e < NN; e += 256) s += c[e] * c[e];
    red[tid] = s; __syncthreads();
    for (int off = 128; off; off >>= 1) { if (tid < off) red[tid] += red[tid + off]; __syncthreads(); }
    if (tid == 0) sig2[col] = red[0];
}

__global__ void select_k(const float* __restrict__ sig2, int* __restrict__ sel)
{
    int i = blockIdx.x * 256 + threadIdx.x;
    if (i >= NN) return;
    float di = sig2[i]; int rank = 0;
    for (int j = 0; j < NN; ++j) {
        float dj = sig2[j];
        rank += (dj < di) || (dj == di && j < i);
    }
    if (rank < LL) sel[rank] = i;
}

__global__ void gather_M(const float* __restrict__ W, const float* __restrict__ sig2,
                         const int* __restrict__ sel, const int* __restrict__ occ,
                         float* __restrict__ Mt)
{
    int idx = blockIdx.x * 256 + threadIdx.x;
    int b = idx >> 10, a = idx & (LL - 1);
    int col = sel[b];
    float rn = 1.f / sqrtf(sig2[col]);
    Mt[(size_t)b * LL + a] = W[(size_t)col * NN + occ[a]] * rn;
}

// G = Mt^T * Mt in fp64 (= M M^T)
__global__ void gram(const float* __restrict__ Mt, double* __restrict__ G)
{
    __shared__ float As[32][17], Bs[32][17];
    int t = threadIdx.x;
    int tx = t & 15, ty = t >> 4;
    int a0 = blockIdx.y * 16, c0 = blockIdx.x * 16;
    double s = 0.0;
    for (int kb = 0; kb < LL; kb += 32) {
        for (int u = t; u < 32 * 16; u += 256) {
            int kr = u >> 4, i = u & 15;
            As[kr][i] = Mt[(size_t)(kb + kr) * LL + a0 + i];
            Bs[kr][i] = Mt[(size_t)(kb + kr) * LL + c0 + i];
        }
        __syncthreads();
        #pragma unroll 8
        for (int k2 = 0; k2 < 32; ++k2)
            s += (double)As[k2][ty] * (double)Bs[k2][tx];
        __syncthreads();
    }
    G[(size_t)(a0 + ty) * LL + (c0 + tx)] = s;
}

// --------------------- blocked fp64 Cholesky (panel 64) ---------------------
__global__ void chol_panel(double* __restrict__ G, int k0, double* __restrict__ acc)
{
    __shared__ double Ld[64][65];
    __shared__ double sinv;
    int tid = threadIdx.x;
    for (int u = tid; u < 4096; u += 256)
        Ld[u >> 6][u & 63] = G[(size_t)(k0 + (u >> 6)) * LL + k0 + (u & 63)];
    __syncthreads();
    double lsum = 0.0;
    for (int c = 0; c < 64; ++c) {
        if (tid == 0) {
            double d = Ld[c][c]; d = d > 1e-300 ? d : 1e-300;
            double sd = sqrt(d); lsum += log(sd);
            Ld[c][c] = sd; sinv = 1.0 / sd;
        }
        __syncthreads();
        if (tid < 63 - c) Ld[c + 1 + tid][c] *= sinv;
        __syncthreads();
        for (int u = tid; u < 4096; u += 256) {
            int rr = u >> 6, cc = u & 63;
            if (rr > c && cc > c) Ld[rr][cc] -= Ld[rr][c] * Ld[cc][c];
        }
        __syncthreads();
    }
    for (int u = tid; u < 4096; u += 256)
        G[(size_t)(k0 + (u >> 6)) * LL + k0 + (u & 63)] = Ld[u >> 6][u & 63];
    if (tid == 0) atomicAdd(acc + 1, lsum);
}

__global__ void chol_trsm(double* __restrict__ G, int k0)
{
    __shared__ double L11[64][65];
    __shared__ double Rt[32][65];
    int tid = threadIdx.x;
    int rbase = k0 + 64 + blockIdx.x * 32;
    for (int u = tid; u < 4096; u += 256)
        L11[u >> 6][u & 63] = G[(size_t)(k0 + (u >> 6)) * LL + k0 + (u & 63)];
    for (int u = tid; u < 2048; u += 256)
        Rt[u >> 6][u & 63] = G[(size_t)(rbase + (u >> 6)) * LL + k0 + (u & 63)];
    __syncthreads();
    for (int c = 0; c < 64; ++c) {
        if (tid < 32) Rt[tid][c] *= 1.0 / L11[c][c];
        __syncthreads();
        for (int u = tid; u < 2048; u += 256) {
            int rr = u >> 6, cc = u & 63;
            if (cc > c) Rt[rr][cc] -= Rt[rr][c] * L11[cc][c];
        }
        __syncthreads();
    }
    for (int u = tid; u < 2048; u += 256)
        G[(size_t)(rbase + (u >> 6)) * LL + k0 + (u & 63)] = Rt[u >> 6][u & 63];
}

__global__ void chol_syrk(double* __restrict__ G, int k0)
{
    __shared__ double At[64][32];
    __shared__ double Bt[64][32];
    int tid = threadIdx.x;
    int r0g = k0 + 64 + blockIdx.y * 64;
    int c0g = k0 + 64 + blockIdx.x * 64;
    int i0 = (tid >> 4) << 2, j0 = (tid & 15) << 2;
    double acc[4][4] = {};
    for (int kh = 0; kh < 2; ++kh) {
        for (int u = tid; u < 2048; u += 256) {
            int i = u >> 5, c = u & 31;
            At[i][c] = G[(size_t)(r0g + i) * LL + k0 + kh * 32 + c];
            Bt[i][c] = G[(size_t)(c0g + i) * LL + k0 + kh * 32 + c];
        }
        __syncthreads();
        for (int c = 0; c < 32; ++c) {
            int cr = (c + tid) & 31;
            double a[4], b[4];
            #pragma unroll
            for (int i = 0; i < 4; ++i) a[i] = At[i0 + i][cr];
            #pragma unroll
            for (int j = 0; j < 4; ++j) b[j] = Bt[j0 + j][cr];
            #pragma unroll
            for (int i = 0; i < 4; ++i)
                #pragma unroll
                for (int j = 0; j < 4; ++j)
                    acc[i][j] += a[i] * b[j];
        }
        __syncthreads();
    }
    #pragma unroll
    for (int i = 0; i < 4; ++i)
        #pragma unroll
        for (int j = 0; j < 4; ++j) {
            size_t e = (size_t)(r0g + i0 + i) * LL + c0g + j0 + j;
            G[e] -= acc[i][j];
        }
}

// --------- all O(L^2) circulant quadratic forms + coherent terms ------------
__global__ void pair_sums(const float* __restrict__ Sz,  const float* __restrict__ X,
                          const float* __restrict__ Y,
                          const float* __restrict__ Jsp, const float* __restrict__ JXel,
                          const float* __restrict__ JYel,const float* __restrict__ pXX,
                          const float* __restrict__ pXY, const float* __restrict__ pYY,
                          const float* __restrict__ sb,  const float* __restrict__ stx,
                          const float* __restrict__ sty,
                          const float* __restrict__ zx,  const float* __restrict__ zy,
                          const float* __restrict__ xr,  const float* __restrict__ yr,
                          double* __restrict__ acc)
{
    __shared__ float tS[289], tXe[289], tYe[289], tXX[289], tXY[289], tYY[289];
    __shared__ double red[256];
    int tid = threadIdx.x;
    for (int u = tid; u < 289; u += 256) {
        tS[u]  = (u < 288) ? Jsp[u] : 0.f;
        tXX[u] = (u < 288) ? pXX[u] : 0.f;
        tXY[u] = (u < 288) ? pXY[u] : 0.f;
        tYY[u] = (u < 288) ? pYY[u] : 0.f;
        tXe[u] = (u >= 1 && u < 288) ? JXel[u - 1] : 0.f;
        tYe[u] = (u >= 1 && u < 288) ? JYel[u - 1] : 0.f;
    }
    __syncthreads();
    int idx = blockIdx.x * 256 + tid;
    int i = idx >> 10, j = idx & (LL - 1);
    int xi = i >> 5, yi = i & 31, xj = j >> 5, yj = j & 31;
    int dx = (xj - xi) & 31, dy = (yj - yi) & 31;
    int rx = (dx <= 16) ? dx : 32 - dx;
    int ry = (dy <= 16) ? dy : 32 - dy;
    int ti = rx * 17 + ry;
    float si = Sz[i], sj = Sz[j];
    float Xi = X[i], Xj = X[j], Yi = Y[i], Yj = Y[j];
    float sbij = sb[i * LL + j];
    double sum = (double)(si * sj) * (double)tS[ti];
    sum += (double)(Xi * Xj) * (double)tXX[ti];
    sum += (double)(Yi * Xj + Xi * Yj) * (double)tXY[ti];
    sum += (double)(Yi * Yj) * (double)tYY[ti];
    sum += (double)(si * sj * sbij) *
           ((double)tXe[ti] * (double)(Xi - Xj) + (double)tYe[ti] * (double)(Yi - Yj));
    if (i == j) {
        float ex = Xi - zx[0] * stx[i];
        float ey = Yi - zy[0] * sty[i];
        sum -= 0.5 * (double)xr[0] * ex * ex + 0.5 * (double)yr[0] * ey * ey;
    }
    red[tid] = sum; __syncthreads();
    for (int off = 128; off; off >>= 1) { if (tid < off) red[tid] += red[tid + off]; __syncthreads(); }
    if (tid == 0) atomicAdd(&acc[0], red[0]);
}

__global__ void finalize(const double* __restrict__ acc, float* __restrict__ out)
{
    out[0] = (float)(acc[0] + acc[1]);
}

// ---------------------------------------------------------------------------
extern "C" void kernel_launch(void* const* d_in, const int* in_sizes, int n_in,
                              void* d_out, int out_size, void* d_ws, size_t ws_size,
                              hipStream_t stream)
{
    const int*   occ  = (const int*)  d_in[0];
    const float* Sz   = (const float*)d_in[2];
    const float* X    = (const float*)d_in[3];
    const float* Y    = (const float*)d_in[4];
    const float* hv   = (const float*)d_in[5];
    const float* sv   = (const float*)d_in[6];
    const float* dv   = (const float*)d_in[7];
    const float* Jsp  = (const float*)d_in[8];
    const float* JXel = (const float*)d_in[9];
    const float* JYel = (const float*)d_in[10];
    const float* pXX  = (const float*)d_in[11];
    const float* pXY  = (const float*)d_in[12];
    const float* pYY  = (const float*)d_in[13];
    const float* g    = (const float*)d_in[14];
    const float* fS   = (const float*)d_in[15];
    const float* fd   = (const float*)d_in[16];
    const float* zx   = (const float*)d_in[17];
    const float* zy   = (const float*)d_in[18];
    const float* xr   = (const float*)d_in[19];
    const float* yr   = (const float*)d_in[20];
    const float* hop  = (const float*)d_in[21];
    const float* swm  = (const float*)d_in[22];
    const float* dwm  = (const float*)d_in[23];
    const int*   ivic = (const int*)  d_in[24];
    const float* sb   = (const float*)d_in[25];
    const float* stx  = (const float*)d_in[26];
    const float* sty  = (const float*)d_in[27];
    float* out = (float*)d_out;

    char* ws = (char*)d_ws;
    float*  W    = (float*) (ws + 0);           // 16.78 MB
    float*  v0   = (float*) (ws + 16777216);    // 8 KB
    float*  v1   = (float*) (ws + 16785408);    // 4 KB used
    int*    flags= (int*)   (ws + 16789504);    // 128 B
    float*  sig2 = (float*) (ws + 16793600);
    int*    sel  = (int*)   (ws + 16801792);
    float*  Mt   = (float*) (ws + 16805888);    // 4 MB; first 512KB doubles as Vbuf during Jacobi
    double* G    = (double*)(ws + 21000192);    // 8 MB fp64 Gram; doubles as Gpart (fp32) during Jacobi
    double* acc  = (double*)(ws + 29388800);    // 32 doubles
    int*    gctl = (int*)   (ws + 29389056);    // [0]=gconv [1]=streak [2..65]=clean
    float*  Vbuf  = Mt;
    float*  Gpart = (float*)G;

    hipMemsetAsync(acc, 0, 768, stream);        // zeroes acc + gctl
    build_H<<<NN * NN / 256, 256, 0, stream>>>(hop, swm, dwm, hv, sv, dv, X, Y,
                                               ivic, sb, g, fS, fd, W);
    powv_init<<<8, 256, 0, stream>>>(v0);
    for (int it = 0; it < PITER; ++it) {
        const float* vin = (it & 1) ? v1 : v0;
        float* vout = (it & 1) ? v0 : v1;
        matvec<<<NN, 256, 0, stream>>>(W, vin, vout, acc + 8 + it);
    }
    add_shift<<<8, 256, 0, stream>>>(W, acc);

    for (int sw = 0; sw < NSWB; ++sw)
        for (int r = 0; r < 63; ++r) {
            jac_gram <<<512, 256, 0, stream>>>(W, Gpart, gctl, r);
            jac_solve<<<32,  512, 0, stream>>>(Gpart, Vbuf, flags, gctl, r);
            jac_apply<<<512, 256, 0, stream>>>(W, Vbuf, flags, gctl, r);
        }

    colnorms<<<NN, 256, 0, stream>>>(W, sig2);
    select_k<<<8, 256, 0, stream>>>(sig2, sel);
    gather_M<<<4096, 256, 0, stream>>>(W, sig2, sel, occ, Mt);
    gram<<<dim3(64, 64), 256, 0, stream>>>(Mt, G);

    for (int s = 0; s < 16; ++s) {
        int k0 = s * 64;
        chol_panel<<<1, 256, 0, stream>>>(G, k0, acc);
        int nrows = LL - k0 - 64;
        if (nrows > 0) {
            chol_trsm<<<nrows / 32, 256, 0, stream>>>(G, k0);
            chol_syrk<<<dim3(nrows / 64, nrows / 64), 256, 0, stream>>>(G, k0);
        }
    }

    pair_sums<<<4096, 256, 0, stream>>>(Sz, X, Y, Jsp, JXel, JYel, pXX, pXY, pYY,
                                        sb, stx, sty, zx, zy, xr, yr, acc);
    finalize<<<1, 1, 0, stream>>>(acc, out);
}